// Round 6
// baseline (433.269 us; speedup 1.0000x reference)
//
#include <hip/hip_runtime.h>

#define NPROT 12288
#define NMOL  6144
#define HID   256
#define NB    32

// bf16 scratch layout (u16-element offsets, base = ws + 1024)
#define PROT_O 0
#define MOL_O  3145728
#define WQ_O   4718592
#define WK_O   4784128
#define WV_O   4849664
#define BQ_O   4915200
#define BK_O   4915456
#define BV_O   4915712
#define Q_O    4915968
#define K_O    8061696
#define VT_O   9634560
#define END_O  11207424

typedef __attribute__((ext_vector_type(4))) float f32x4;
typedef __attribute__((ext_vector_type(8))) short bf16x8;
typedef unsigned short u16;
typedef unsigned int   u32;

__device__ __forceinline__ float b2f(u16 u){
  union { u32 i; float f; } v; v.i = ((u32)u) << 16; return v.f;
}
__device__ __forceinline__ u16 f2b(float f){
  union { float fl; u32 i; } v; v.fl = f;
  u32 i = v.i;
  return (u16)((i + 0x7FFFu + ((i >> 16) & 1u)) >> 16);  // RNE
}

// ---------------------------------------------------------------------------
// Convert: f32 -> bf16 for all inputs into ws (4801 blocks x 256 thr, one
// quad each). Block 0 wave 0 additionally computes per-batch ranges via 64
// binary searches: rg[b]/rg[32+b] = prot start/end, rg[64+b]/rg[96+b] = mol.
// ---------------------------------------------------------------------------
__global__ __launch_bounds__(256) void convert_kernel(
    const float* __restrict__ prot, const float* __restrict__ mol,
    const float* __restrict__ Wq, const float* __restrict__ Wk,
    const float* __restrict__ Wv, const float* __restrict__ bq,
    const float* __restrict__ bk, const float* __restrict__ bv,
    const int* __restrict__ pb, const int* __restrict__ mb,
    int* __restrict__ rg, u16* __restrict__ cvt)
{
  int g = blockIdx.x * 256 + threadIdx.x;   // quad index
  const float* src = nullptr; u16* dst = nullptr; int off = 0;
  if      (g < 786432)  { src = prot; dst = cvt + PROT_O; off = g; }
  else if (g < 1179648) { src = mol;  dst = cvt + MOL_O;  off = g - 786432; }
  else if (g < 1196032) { src = Wq;   dst = cvt + WQ_O;   off = g - 1179648; }
  else if (g < 1212416) { src = Wk;   dst = cvt + WK_O;   off = g - 1196032; }
  else if (g < 1228800) { src = Wv;   dst = cvt + WV_O;   off = g - 1212416; }
  else if (g < 1228864) { src = bq;   dst = cvt + BQ_O;   off = g - 1228800; }
  else if (g < 1228928) { src = bk;   dst = cvt + BK_O;   off = g - 1228864; }
  else if (g < 1228992) { src = bv;   dst = cvt + BV_O;   off = g - 1228928; }
  if (src){
    f32x4 v = *(const f32x4*)(src + (size_t)off * 4);
    ushort4 o;
    o.x = f2b(v[0]); o.y = f2b(v[1]); o.z = f2b(v[2]); o.w = f2b(v[3]);
    *(ushort4*)(dst + (size_t)off * 4) = o;
  }

  if (blockIdx.x == 0 && threadIdx.x < 64){
    int t = threadIdx.x;
    const int* arr = (t < 32) ? pb : mb;
    int n          = (t < 32) ? NPROT : NMOL;
    int target     = (t & 31) + 1;
    int lo = 0, hi = n;
    while (lo < hi){                // lower_bound(target)
      int mid = (lo + hi) >> 1;
      if (arr[mid] < target) lo = mid + 1; else hi = mid;
    }
    int end = lo;
    int prev = __shfl(end, t - 1);  // end of batch b-1 == start of batch b
    int start = ((t & 31) == 0) ? 0 : prev;
    int b = t & 31;
    if (t < 32){ rg[b] = start; rg[32 + b] = end; }
    else       { rg[64 + b] = start; rg[96 + b] = end; }
  }
}

// ---------------------------------------------------------------------------
// Projections (bf16 in ws): out[i][j] = sum_k x[i][k]*W[j][k] + b[j]
// grid (384, 4): x<192 -> Q, x<288 -> K, else V (stored transposed Vt[h][mol]).
// Wave computes a 16x64 tile. C/D layout: col=lane&15, row=(lane>>4)*4+reg.
// ---------------------------------------------------------------------------
__global__ __launch_bounds__(256) void proj_kernel(
    const u16* __restrict__ cvt,
    u16* __restrict__ Q, u16* __restrict__ K, u16* __restrict__ Vt)
{
  __shared__ u16 tlds[4][64][18];
  int x = blockIdx.x;
  int proj, rowblk;
  if      (x < 192){ proj = 0; rowblk = x; }
  else if (x < 288){ proj = 1; rowblk = x - 192; }
  else             { proj = 2; rowblk = x - 288; }
  const u16 *X, *W, *B;
  if (proj == 0){ X = cvt + PROT_O; W = cvt + WQ_O; B = cvt + BQ_O; }
  else if (proj == 1){ X = cvt + MOL_O; W = cvt + WK_O; B = cvt + BK_O; }
  else { X = cvt + MOL_O; W = cvt + WV_O; B = cvt + BV_O; }

  int wave = threadIdx.x >> 6, lane = threadIdx.x & 63;
  int m = lane & 15, q = lane >> 4;
  int rowbase = rowblk * 64 + wave * 16;
  int colbase = blockIdx.y * 64;

  const u16* arow = X + (size_t)(rowbase + m) * HID;
  f32x4 acc[4] = {};
  for (int k0 = 0; k0 < HID; k0 += 32){
    bf16x8 a = *(const bf16x8*)(arow + k0 + q*8);
    #pragma unroll
    for (int ct = 0; ct < 4; ct++){
      bf16x8 b = *(const bf16x8*)(W + (size_t)(colbase + ct*16 + m) * HID + k0 + q*8);
      acc[ct] = __builtin_amdgcn_mfma_f32_16x16x32_bf16(a, b, acc[ct], 0, 0, 0);
    }
  }

  if (proj < 2){
    u16* O = (proj == 0) ? Q : K;
    #pragma unroll
    for (int ct = 0; ct < 4; ct++){
      int col = colbase + ct*16 + m;
      float bb = b2f(B[col]);
      #pragma unroll
      for (int r = 0; r < 4; r++){
        int row = rowbase + q*4 + r;
        O[(size_t)row * HID + col] = f2b(acc[ct][r] + bb);
      }
    }
  } else {
    #pragma unroll
    for (int ct = 0; ct < 4; ct++){
      int lc = ct*16 + m;
      float bb = b2f(B[colbase + lc]);
      #pragma unroll
      for (int r = 0; r < 4; r++)
        tlds[wave][lc][q*4 + r] = f2b(acc[ct][r] + bb);
    }
    __syncthreads();
    int col = colbase + lane;
    u32 packed[8];
    #pragma unroll
    for (int i = 0; i < 8; i++){
      u16 lo = tlds[wave][lane][2*i];
      u16 hi = tlds[wave][lane][2*i+1];
      packed[i] = (u32)lo | ((u32)hi << 16);
    }
    u16* dst = Vt + (size_t)col * NMOL + rowbase;
    uint4 v0 = {packed[0], packed[1], packed[2], packed[3]};
    uint4 v1 = {packed[4], packed[5], packed[6], packed[7]};
    *(uint4*)dst = v0;
    *(uint4*)(dst + 8) = v1;
  }
}

// ---------------------------------------------------------------------------
// Attention (f32 out): attn region pre-zeroed by hipMemsetAsync, so this
// kernel writes ONLY the block-diagonal P values + O. One block (4 waves)
// per 16-row tile; waves split the mol range; softmax state merged via LDS;
// O reduced across waves via LDS.
// ---------------------------------------------------------------------------
__global__ __launch_bounds__(256) void attn_kernel(
    const int* __restrict__ rg, const u16* __restrict__ Q, const u16* __restrict__ K,
    const u16* __restrict__ Vt, float* __restrict__ dout)
{
  __shared__ u16 plds[4][16][48];
  __shared__ float mxw[4][16];
  __shared__ float smw[4][16];
  __shared__ float red[2][4096];
  const float scale = 0.0625f;     // 1/sqrt(256)
  int b = blockIdx.y;
  int ps = rg[b], pe = rg[32+b], ms = rg[64+b], me = rg[96+b];
  int Np = pe - ps, Nm = me - ms;
  if (Np <= 0) return;

  int wave = threadIdx.x >> 6, lane = threadIdx.x & 63;
  int m = lane & 15, q = lane >> 4;
  float* outf  = dout;
  float* attnf = dout + (size_t)NPROT * HID;
  int ntiles = (Np + 15) >> 4;

  int bs = 0, ce = 0;
  if (Nm > 0){ bs = ms & ~31; ce = bs + ((me - bs + 31) & ~31); }  // ce <= NMOL

  for (int tile = blockIdx.x; tile < ntiles; tile += gridDim.x){
    int row0 = ps + tile * 16;

    int qr = min(row0 + m, NPROT - 1);
    const u16* qrow = Q + (size_t)qr * HID;
    bf16x8 qf[8];
    #pragma unroll
    for (int kk = 0; kk < 8; kk++)
      qf[kk] = *(const bf16x8*)(qrow + kk*32 + q*8);

    if (Nm > 0){
      // ---- phase A: per-wave online max+sum over its column strip ----
      float mx[4] = {-1e30f, -1e30f, -1e30f, -1e30f};
      float sm[4] = {0.f, 0.f, 0.f, 0.f};
      for (int j0 = bs + wave*16; j0 < me; j0 += 64){
        int col = j0 + m;
        bool valid = (col >= ms) && (col < me);
        const u16* krow = K + (size_t)min(col, NMOL-1) * HID;
        f32x4 s0 = {0.f,0.f,0.f,0.f}, s1 = {0.f,0.f,0.f,0.f};
        #pragma unroll
        for (int kk = 0; kk < 4; kk++){
          bf16x8 kb0 = *(const bf16x8*)(krow + kk*32 + q*8);
          bf16x8 kb1 = *(const bf16x8*)(krow + (kk+4)*32 + q*8);
          s0 = __builtin_amdgcn_mfma_f32_16x16x32_bf16(qf[kk],   kb0, s0, 0, 0, 0);
          s1 = __builtin_amdgcn_mfma_f32_16x16x32_bf16(qf[kk+4], kb1, s1, 0, 0, 0);
        }
        f32x4 s = s0 + s1;
        float sv[4], cm[4];
        #pragma unroll
        for (int r = 0; r < 4; r++){
          sv[r] = valid ? s[r] * scale : -1e30f;
          cm[r] = sv[r];
        }
        #pragma unroll
        for (int d = 1; d < 16; d <<= 1)
          #pragma unroll
          for (int r = 0; r < 4; r++)
            cm[r] = fmaxf(cm[r], __shfl_xor(cm[r], d, 16));
        float e[4];
        #pragma unroll
        for (int r = 0; r < 4; r++){
          float mn = fmaxf(mx[r], cm[r]);
          float corr = __expf(mx[r] - mn);
          e[r] = __expf(sv[r] - mn);
          mx[r] = mn;
          sm[r] = sm[r] * corr;
        }
        #pragma unroll
        for (int d = 1; d < 16; d <<= 1)
          #pragma unroll
          for (int r = 0; r < 4; r++)
            e[r] += __shfl_xor(e[r], d, 16);
        #pragma unroll
        for (int r = 0; r < 4; r++) sm[r] += e[r];
      }
      if (m == 0){
        #pragma unroll
        for (int r = 0; r < 4; r++){
          mxw[wave][q*4 + r] = mx[r];
          smw[wave][q*4 + r] = sm[r];
        }
      }
      __syncthreads();

      float gmx[4], ginv[4];
      #pragma unroll
      for (int r = 0; r < 4; r++){
        int row = q*4 + r;
        float M = mxw[0][row];
        #pragma unroll
        for (int w = 1; w < 4; w++) M = fmaxf(M, mxw[w][row]);
        float S = 0.f;
        #pragma unroll
        for (int w = 0; w < 4; w++) S += smw[w][row] * __expf(mxw[w][row] - M);
        gmx[r] = M;
        ginv[r] = (S > 0.f) ? (1.f / S) : 0.f;
      }

      // ---- phase B: P stores (block cols only) + PV ----
      f32x4 oacc[16] = {};
      for (int j0 = bs + wave*32; j0 < ce; j0 += 128){
        #pragma unroll
        for (int sub = 0; sub < 2; sub++){
          int col = j0 + sub*16 + m;
          bool valid = (col >= ms) && (col < me);
          const u16* krow = K + (size_t)col * HID;   // col < ce <= NMOL
          f32x4 s0 = {0.f,0.f,0.f,0.f}, s1 = {0.f,0.f,0.f,0.f};
          #pragma unroll
          for (int kk = 0; kk < 4; kk++){
            bf16x8 kb0 = *(const bf16x8*)(krow + kk*32 + q*8);
            bf16x8 kb1 = *(const bf16x8*)(krow + (kk+4)*32 + q*8);
            s0 = __builtin_amdgcn_mfma_f32_16x16x32_bf16(qf[kk],   kb0, s0, 0, 0, 0);
            s1 = __builtin_amdgcn_mfma_f32_16x16x32_bf16(qf[kk+4], kb1, s1, 0, 0, 0);
          }
          f32x4 s = s0 + s1;
          #pragma unroll
          for (int r = 0; r < 4; r++){
            float pv = valid ? __expf(s[r]*scale - gmx[r]) * ginv[r] : 0.f;
            u16 pb16 = f2b(pv);
            plds[wave][q*4 + r][sub*16 + m] = pb16;
            int row = row0 + q*4 + r;
            if (valid && row < pe) attnf[(size_t)row * NMOL + col] = pv;
          }
        }
        bf16x8 a = *(const bf16x8*)(&plds[wave][m][q*8]);
        int kbase = j0 + q*8;
        #pragma unroll
        for (int ct = 0; ct < 16; ct++){
          bf16x8 vb = *(const bf16x8*)(Vt + (size_t)(ct*16 + m) * NMOL + kbase);
          oacc[ct] = __builtin_amdgcn_mfma_f32_16x16x32_bf16(a, vb, oacc[ct], 0, 0, 0);
        }
      }
      __syncthreads();

      // ---- 2-stage O reduction across waves ----
      if (wave == 1 || wave == 3){
        float* dst = red[(wave - 1) >> 1];
        #pragma unroll
        for (int ct = 0; ct < 16; ct++)
          #pragma unroll
          for (int r = 0; r < 4; r++)
            dst[(ct*4 + r)*64 + lane] = oacc[ct][r];
      }
      __syncthreads();
      if (wave == 0 || wave == 2){
        const float* src = red[wave >> 1];
        #pragma unroll
        for (int ct = 0; ct < 16; ct++)
          #pragma unroll
          for (int r = 0; r < 4; r++)
            oacc[ct][r] += src[(ct*4 + r)*64 + lane];
      }
      __syncthreads();
      if (wave == 2){
        #pragma unroll
        for (int ct = 0; ct < 16; ct++)
          #pragma unroll
          for (int r = 0; r < 4; r++)
            red[0][(ct*4 + r)*64 + lane] = oacc[ct][r];
      }
      __syncthreads();
      if (wave == 0){
        #pragma unroll
        for (int ct = 0; ct < 16; ct++){
          int colh = ct*16 + m;
          #pragma unroll
          for (int r = 0; r < 4; r++){
            float o = oacc[ct][r] + red[0][(ct*4 + r)*64 + lane];
            int row = row0 + q*4 + r;
            if (row < pe) outf[(size_t)row * HID + colh] = o;
          }
        }
      }
    } else {
      if (wave == 0){
        #pragma unroll
        for (int ct = 0; ct < 16; ct++){
          int colh = ct*16 + m;
          #pragma unroll
          for (int r = 0; r < 4; r++){
            int row = row0 + q*4 + r;
            if (row < pe) outf[(size_t)row * HID + colh] = 0.f;
          }
        }
      }
    }
    __syncthreads();   // protect LDS reuse across tile iterations
  }
}

extern "C" void kernel_launch(void* const* d_in, const int* in_sizes, int n_in,
                              void* d_out, int out_size, void* d_ws, size_t ws_size,
                              hipStream_t stream)
{
  (void)in_sizes; (void)n_in; (void)out_size;
  const float* prot = (const float*)d_in[0];
  const float* mol  = (const float*)d_in[1];
  const int* pb     = (const int*)d_in[2];
  const int* mb     = (const int*)d_in[3];
  const float* Wq   = (const float*)d_in[4];
  const float* bq   = (const float*)d_in[5];
  const float* Wk   = (const float*)d_in[6];
  const float* bk   = (const float*)d_in[7];
  const float* Wv   = (const float*)d_in[8];
  const float* bv   = (const float*)d_in[9];

  const size_t need = 1024 + (size_t)END_O * 2;
  if (ws_size < need) return;

  char* ws = (char*)d_ws;
  int* rg  = (int*)ws;
  u16* cvt = (u16*)(ws + 1024);
  u16* Qp  = cvt + Q_O;
  u16* Kp  = cvt + K_O;
  u16* Vtp = cvt + VT_O;

  // bulk-zero the attn region at runtime fill BW (~6 TB/s); attn_kernel then
  // writes only the block-diagonal P values on top.
  hipMemsetAsync((char*)d_out + (size_t)NPROT * HID * 4, 0,
                 (size_t)NPROT * NMOL * 4, stream);
  convert_kernel<<<dim3(4801), dim3(256), 0, stream>>>(
      prot, mol, Wq, Wk, Wv, bq, bk, bv, pb, mb, rg, cvt);
  proj_kernel<<<dim3(384, 4), dim3(256), 0, stream>>>(cvt, Qp, Kp, Vtp);
  attn_kernel<<<dim3(32, NB), dim3(256), 0, stream>>>(rg, Qp, Kp, Vtp, (float*)d_out);
}

// Round 7
// 407.425 us; speedup vs baseline: 1.0634x; 1.0634x over previous
//
#include <hip/hip_runtime.h>

#define NPROT 12288
#define NMOL  6144
#define HID   256
#define NB    32

// bf16 scratch layout (u16-element offsets, base = ws + 1024)
#define PROT_O 0
#define MOL_O  3145728
#define WQ_O   4718592
#define WK_O   4784128
#define WV_O   4849664
#define BQ_O   4915200
#define BK_O   4915456
#define BV_O   4915712
#define Q_O    4915968
#define K_O    8061696
#define VT_O   9634560
#define END_O  11207424

// attn-region fill: 75,497,472 floats split in two halves of 512 blocks
#define FILL_BLOCKS 512
#define FILL_CHUNK  73728          // floats per fill block (= 288 KB)
#define FILL_HALF   37748736       // floats per half

typedef __attribute__((ext_vector_type(4))) float f32x4;
typedef __attribute__((ext_vector_type(8))) short bf16x8;
typedef unsigned short u16;
typedef unsigned int   u32;

__device__ __forceinline__ float b2f(u16 u){
  union { u32 i; float f; } v; v.i = ((u32)u) << 16; return v.f;
}
__device__ __forceinline__ u16 f2b(float f){
  union { float fl; u32 i; } v; v.fl = f;
  u32 i = v.i;
  return (u16)((i + 0x7FFFu + ((i >> 16) & 1u)) >> 16);  // RNE
}

__device__ __forceinline__ void fill_zero(float* attnf, int idx){
  float* dst = attnf + (size_t)idx * FILL_CHUNK + threadIdx.x * 4;
  f32x4 z = {0.f, 0.f, 0.f, 0.f};
  #pragma unroll 4
  for (int i = 0; i < 72; i++)
    __builtin_nontemporal_store(z, (f32x4*)(dst + i * 1024));
}

// ---------------------------------------------------------------------------
// Convert: f32 -> bf16 for all inputs into ws; block 0 wave 0 computes
// per-batch ranges via binary search; blocks >= 4801 zero-fill the first
// half of the attn output region (overlapped with the read-bound convert).
// ---------------------------------------------------------------------------
__global__ __launch_bounds__(256) void convert_kernel(
    const float* __restrict__ prot, const float* __restrict__ mol,
    const float* __restrict__ Wq, const float* __restrict__ Wk,
    const float* __restrict__ Wv, const float* __restrict__ bq,
    const float* __restrict__ bk, const float* __restrict__ bv,
    const int* __restrict__ pb, const int* __restrict__ mb,
    int* __restrict__ rg, u16* __restrict__ cvt, float* __restrict__ dout)
{
  if (blockIdx.x >= 4801){
    fill_zero(dout + (size_t)NPROT * HID, blockIdx.x - 4801);
    return;
  }
  int g = blockIdx.x * 256 + threadIdx.x;   // quad index
  const float* src = nullptr; u16* dst = nullptr; int off = 0;
  if      (g < 786432)  { src = prot; dst = cvt + PROT_O; off = g; }
  else if (g < 1179648) { src = mol;  dst = cvt + MOL_O;  off = g - 786432; }
  else if (g < 1196032) { src = Wq;   dst = cvt + WQ_O;   off = g - 1179648; }
  else if (g < 1212416) { src = Wk;   dst = cvt + WK_O;   off = g - 1196032; }
  else if (g < 1228800) { src = Wv;   dst = cvt + WV_O;   off = g - 1212416; }
  else if (g < 1228864) { src = bq;   dst = cvt + BQ_O;   off = g - 1228800; }
  else if (g < 1228928) { src = bk;   dst = cvt + BK_O;   off = g - 1228864; }
  else if (g < 1228992) { src = bv;   dst = cvt + BV_O;   off = g - 1228928; }
  if (src){
    f32x4 v = *(const f32x4*)(src + (size_t)off * 4);
    ushort4 o;
    o.x = f2b(v[0]); o.y = f2b(v[1]); o.z = f2b(v[2]); o.w = f2b(v[3]);
    *(ushort4*)(dst + (size_t)off * 4) = o;
  }

  if (blockIdx.x == 0 && threadIdx.x < 64){
    int t = threadIdx.x;
    const int* arr = (t < 32) ? pb : mb;
    int n          = (t < 32) ? NPROT : NMOL;
    int target     = (t & 31) + 1;
    int lo = 0, hi = n;
    while (lo < hi){                // lower_bound(target)
      int mid = (lo + hi) >> 1;
      if (arr[mid] < target) lo = mid + 1; else hi = mid;
    }
    int end = lo;
    int prev = __shfl(end, t - 1);  // end of batch b-1 == start of batch b
    int start = ((t & 31) == 0) ? 0 : prev;
    int b = t & 31;
    if (t < 32){ rg[b] = start; rg[32 + b] = end; }
    else       { rg[64 + b] = start; rg[96 + b] = end; }
  }
}

// ---------------------------------------------------------------------------
// Projections (bf16 in ws): out[i][j] = sum_k x[i][k]*W[j][k] + b[j]
// 1-D grid: x<1536 -> proj tiles (rowblk=x>>2, colblk=x&3); x>=1536 ->
// zero-fill the second half of the attn region. Wave computes a 16x64 tile.
// C/D layout: col=lane&15, row=(lane>>4)*4+reg.
// ---------------------------------------------------------------------------
__global__ __launch_bounds__(256) void proj_kernel(
    const u16* __restrict__ cvt,
    u16* __restrict__ Q, u16* __restrict__ K, u16* __restrict__ Vt,
    float* __restrict__ dout)
{
  __shared__ u16 tlds[4][64][18];
  if (blockIdx.x >= 1536){
    fill_zero(dout + (size_t)NPROT * HID + FILL_HALF, blockIdx.x - 1536);
    return;
  }
  int rowblk = blockIdx.x >> 2, colblk = blockIdx.x & 3;
  int proj;
  if      (rowblk < 192){ proj = 0; }
  else if (rowblk < 288){ proj = 1; rowblk -= 192; }
  else                  { proj = 2; rowblk -= 288; }
  const u16 *X, *W, *B;
  if (proj == 0){ X = cvt + PROT_O; W = cvt + WQ_O; B = cvt + BQ_O; }
  else if (proj == 1){ X = cvt + MOL_O; W = cvt + WK_O; B = cvt + BK_O; }
  else { X = cvt + MOL_O; W = cvt + WV_O; B = cvt + BV_O; }

  int wave = threadIdx.x >> 6, lane = threadIdx.x & 63;
  int m = lane & 15, q = lane >> 4;
  int rowbase = rowblk * 64 + wave * 16;
  int colbase = colblk * 64;

  const u16* arow = X + (size_t)(rowbase + m) * HID;
  f32x4 acc[4] = {};
  for (int k0 = 0; k0 < HID; k0 += 32){
    bf16x8 a = *(const bf16x8*)(arow + k0 + q*8);
    #pragma unroll
    for (int ct = 0; ct < 4; ct++){
      bf16x8 b = *(const bf16x8*)(W + (size_t)(colbase + ct*16 + m) * HID + k0 + q*8);
      acc[ct] = __builtin_amdgcn_mfma_f32_16x16x32_bf16(a, b, acc[ct], 0, 0, 0);
    }
  }

  if (proj < 2){
    u16* O = (proj == 0) ? Q : K;
    #pragma unroll
    for (int ct = 0; ct < 4; ct++){
      int col = colbase + ct*16 + m;
      float bb = b2f(B[col]);
      #pragma unroll
      for (int r = 0; r < 4; r++){
        int row = rowbase + q*4 + r;
        O[(size_t)row * HID + col] = f2b(acc[ct][r] + bb);
      }
    }
  } else {
    #pragma unroll
    for (int ct = 0; ct < 4; ct++){
      int lc = ct*16 + m;
      float bb = b2f(B[colbase + lc]);
      #pragma unroll
      for (int r = 0; r < 4; r++)
        tlds[wave][lc][q*4 + r] = f2b(acc[ct][r] + bb);
    }
    __syncthreads();
    int col = colbase + lane;
    u32 packed[8];
    #pragma unroll
    for (int i = 0; i < 8; i++){
      u16 lo = tlds[wave][lane][2*i];
      u16 hi = tlds[wave][lane][2*i+1];
      packed[i] = (u32)lo | ((u32)hi << 16);
    }
    u16* dst = Vt + (size_t)col * NMOL + rowbase;
    uint4 v0 = {packed[0], packed[1], packed[2], packed[3]};
    uint4 v1 = {packed[4], packed[5], packed[6], packed[7]};
    *(uint4*)dst = v0;
    *(uint4*)(dst + 8) = v1;
  }
}

// ---------------------------------------------------------------------------
// Attention (f32 out): attn region pre-zeroed by the fill blocks, so this
// kernel writes only block-diagonal P + O. Single QK^T: each wave keeps its
// strip's scores in REGISTERS (<=6 f32x4, fixed-index unroll).
//   A: S = QK^T (strip, regs) + row max      -> merge max via LDS
//   B: e = exp(s-gmx) (regs) + partial sums  -> merge sums via LDS
//   C: p = e*ginv -> attn global + P LDS (bf16)
//   D: PV with waves splitting HID (4 MFMA cols each) -> no O reduction
// ---------------------------------------------------------------------------
__global__ __launch_bounds__(256) void attn_kernel(
    const int* __restrict__ rg, const u16* __restrict__ Q, const u16* __restrict__ K,
    const u16* __restrict__ Vt, float* __restrict__ dout)
{
  __shared__ u16 P[16][392];        // P tile bf16, cols [bs,ce), pad->392
  __shared__ float mxw[4][16];
  __shared__ float smw[4][16];
  const float scale = 0.0625f;      // 1/sqrt(256)
  int b = blockIdx.y;
  int ps = rg[b], pe = rg[32+b], ms = rg[64+b], me = rg[96+b];
  int Np = pe - ps, Nm = me - ms;
  if (Np <= 0) return;

  int wave = threadIdx.x >> 6, lane = threadIdx.x & 63;
  int m = lane & 15, q = lane >> 4;
  float* outf  = dout;
  float* attnf = dout + (size_t)NPROT * HID;
  int ntiles = (Np + 15) >> 4;

  int bs = 0, ce = 0;
  if (Nm > 0){ bs = ms & ~31; ce = bs + ((me - bs + 31) & ~31); }  // ce <= NMOL

  for (int tile = blockIdx.x; tile < ntiles; tile += gridDim.x){
    int row0 = ps + tile * 16;
    int qr = min(row0 + m, NPROT - 1);
    const u16* qrow = Q + (size_t)qr * HID;
    bf16x8 qf[8];
    #pragma unroll
    for (int kk = 0; kk < 8; kk++)
      qf[kk] = *(const bf16x8*)(qrow + kk*32 + q*8);

    if (Nm > 0){
      int myj0 = bs + wave * 16;
      // ---- phase A: single QK^T pass, scores -> registers, track max ----
      f32x4 sreg[6];
      float mx[4] = {-1e30f, -1e30f, -1e30f, -1e30f};
      #pragma unroll
      for (int c = 0; c < 6; c++){
        int j0 = myj0 + 64*c;
        if (j0 < ce){
          int col = j0 + m;                         // col <= ce-1 < NMOL
          bool valid = (col >= ms) && (col < me);
          const u16* krow = K + (size_t)col * HID;
          f32x4 s0 = {0.f,0.f,0.f,0.f}, s1 = {0.f,0.f,0.f,0.f};
          #pragma unroll
          for (int kk = 0; kk < 4; kk++){
            bf16x8 kb0 = *(const bf16x8*)(krow + kk*32 + q*8);
            bf16x8 kb1 = *(const bf16x8*)(krow + (kk+4)*32 + q*8);
            s0 = __builtin_amdgcn_mfma_f32_16x16x32_bf16(qf[kk],   kb0, s0, 0, 0, 0);
            s1 = __builtin_amdgcn_mfma_f32_16x16x32_bf16(qf[kk+4], kb1, s1, 0, 0, 0);
          }
          f32x4 sv;
          #pragma unroll
          for (int r = 0; r < 4; r++)
            sv[r] = valid ? (s0[r] + s1[r]) * scale : -1e30f;
          sreg[c] = sv;
          float cm[4];
          #pragma unroll
          for (int r = 0; r < 4; r++) cm[r] = sv[r];
          #pragma unroll
          for (int d = 1; d < 16; d <<= 1)
            #pragma unroll
            for (int r = 0; r < 4; r++)
              cm[r] = fmaxf(cm[r], __shfl_xor(cm[r], d, 16));
          #pragma unroll
          for (int r = 0; r < 4; r++) mx[r] = fmaxf(mx[r], cm[r]);
        }
      }
      if (m == 0){
        #pragma unroll
        for (int r = 0; r < 4; r++) mxw[wave][q*4 + r] = mx[r];
      }
      __syncthreads();
      float gmx[4];
      #pragma unroll
      for (int r = 0; r < 4; r++){
        int row = q*4 + r;
        float M = mxw[0][row];
        #pragma unroll
        for (int w = 1; w < 4; w++) M = fmaxf(M, mxw[w][row]);
        gmx[r] = M;
      }

      // ---- phase B: exponentiate in regs + partial row sums ----
      float sm[4] = {0.f, 0.f, 0.f, 0.f};
      #pragma unroll
      for (int c = 0; c < 6; c++){
        int j0 = myj0 + 64*c;
        if (j0 < ce){
          f32x4 e;
          #pragma unroll
          for (int r = 0; r < 4; r++) e[r] = __expf(sreg[c][r] - gmx[r]);
          sreg[c] = e;
          float t[4];
          #pragma unroll
          for (int r = 0; r < 4; r++) t[r] = e[r];
          #pragma unroll
          for (int d = 1; d < 16; d <<= 1)
            #pragma unroll
            for (int r = 0; r < 4; r++)
              t[r] += __shfl_xor(t[r], d, 16);
          #pragma unroll
          for (int r = 0; r < 4; r++) sm[r] += t[r];
        }
      }
      if (m == 0){
        #pragma unroll
        for (int r = 0; r < 4; r++) smw[wave][q*4 + r] = sm[r];
      }
      __syncthreads();
      float ginv[4];
      #pragma unroll
      for (int r = 0; r < 4; r++){
        int row = q*4 + r;
        float S = smw[0][row] + smw[1][row] + smw[2][row] + smw[3][row];
        ginv[r] = (S > 0.f) ? (1.f / S) : 0.f;
      }

      // ---- phase C: normalize -> attn global + P LDS ----
      #pragma unroll
      for (int c = 0; c < 6; c++){
        int j0 = myj0 + 64*c;
        if (j0 < ce){
          int col = j0 + m;
          int jl = j0 - bs;
          bool valid = (col >= ms) && (col < me);
          #pragma unroll
          for (int r = 0; r < 4; r++){
            float p = sreg[c][r] * ginv[r];
            P[q*4 + r][jl + m] = f2b(p);
            int row = row0 + q*4 + r;
            if (valid && row < pe)
              __builtin_nontemporal_store(p, attnf + (size_t)row * NMOL + col);
          }
        }
      }
      __syncthreads();

      // ---- phase D: PV, waves split HID (ct = wave*4 .. wave*4+3) ----
      f32x4 oacc[4] = {};
      for (int j0 = bs; j0 < ce; j0 += 32){
        int jl = j0 - bs;
        bf16x8 a = *(const bf16x8*)(&P[m][jl + q*8]);
        #pragma unroll
        for (int c2 = 0; c2 < 4; c2++){
          int ct = wave*4 + c2;
          bf16x8 vb = *(const bf16x8*)(Vt + (size_t)(ct*16 + m) * NMOL + j0 + q*8);
          oacc[c2] = __builtin_amdgcn_mfma_f32_16x16x32_bf16(a, vb, oacc[c2], 0, 0, 0);
        }
      }
      #pragma unroll
      for (int c2 = 0; c2 < 4; c2++){
        int col = (wave*4 + c2)*16 + m;
        #pragma unroll
        for (int r = 0; r < 4; r++){
          int row = row0 + q*4 + r;
          if (row < pe) outf[(size_t)row * HID + col] = oacc[c2][r];
        }
      }
    } else {
      // no valid keys: O rows are zeros (waves split HID)
      #pragma unroll
      for (int c2 = 0; c2 < 4; c2++){
        int col = (wave*4 + c2)*16 + m;
        #pragma unroll
        for (int r = 0; r < 4; r++){
          int row = row0 + q*4 + r;
          if (row < pe) outf[(size_t)row * HID + col] = 0.f;
        }
      }
    }
    __syncthreads();   // protect P/mxw/smw reuse across tile iterations
  }
}

extern "C" void kernel_launch(void* const* d_in, const int* in_sizes, int n_in,
                              void* d_out, int out_size, void* d_ws, size_t ws_size,
                              hipStream_t stream)
{
  (void)in_sizes; (void)n_in; (void)out_size;
  const float* prot = (const float*)d_in[0];
  const float* mol  = (const float*)d_in[1];
  const int* pb     = (const int*)d_in[2];
  const int* mb     = (const int*)d_in[3];
  const float* Wq   = (const float*)d_in[4];
  const float* bq   = (const float*)d_in[5];
  const float* Wk   = (const float*)d_in[6];
  const float* bk   = (const float*)d_in[7];
  const float* Wv   = (const float*)d_in[8];
  const float* bv   = (const float*)d_in[9];

  const size_t need = 1024 + (size_t)END_O * 2;
  if (ws_size < need) return;

  char* ws = (char*)d_ws;
  int* rg  = (int*)ws;
  u16* cvt = (u16*)(ws + 1024);
  u16* Qp  = cvt + Q_O;
  u16* Kp  = cvt + K_O;
  u16* Vtp = cvt + VT_O;
  float* out = (float*)d_out;

  convert_kernel<<<dim3(4801 + FILL_BLOCKS), dim3(256), 0, stream>>>(
      prot, mol, Wq, Wk, Wv, bq, bk, bv, pb, mb, rg, cvt, out);
  proj_kernel<<<dim3(1536 + FILL_BLOCKS), dim3(256), 0, stream>>>(
      cvt, Qp, Kp, Vtp, out);
  attn_kernel<<<dim3(32, NB), dim3(256), 0, stream>>>(rg, Qp, Kp, Vtp, out);
}

// Round 8
// 390.077 us; speedup vs baseline: 1.1107x; 1.0445x over previous
//
#include <hip/hip_runtime.h>

#define NPROT 12288
#define NMOL  6144
#define HID   256
#define NB    32

// bf16 scratch layout (u16-element offsets, base = ws + 1024)
#define PROT_O 0
#define MOL_O  3145728
#define WQ_O   4718592
#define WK_O   4784128
#define WV_O   4849664
#define BQ_O   4915200
#define BK_O   4915456
#define BV_O   4915712
#define Q_O    4915968
#define K_O    8061696
#define VT_O   9634560
#define END_O  11207424

// attn-region zero fill, split across all three kernels:
//   convert: 512 blocks x 8 full rows  (rows    0..4095)
//   proj:    512 blocks x 8 full rows  (rows 4096..8191)
//   attn:    256 blocks x 16 rows, skipping each row's live cols [ms,me)
#define FROWS_BLK 49152            // floats per 8-row fill block

typedef __attribute__((ext_vector_type(4))) float f32x4;
typedef __attribute__((ext_vector_type(8))) short bf16x8;
typedef unsigned short u16;
typedef unsigned int   u32;

__device__ __forceinline__ float b2f(u16 u){
  union { u32 i; float f; } v; v.i = ((u32)u) << 16; return v.f;
}
__device__ __forceinline__ u16 f2b(float f){
  union { float fl; u32 i; } v; v.fl = f;
  u32 i = v.i;
  return (u16)((i + 0x7FFFu + ((i >> 16) & 1u)) >> 16);  // RNE
}

// zero 8 contiguous attn rows (fid in [0,1024): rows 8*fid .. 8*fid+7)
__device__ __forceinline__ void fill_rows8(float* attnf, int fid){
  float* dst = attnf + (size_t)fid * FROWS_BLK + threadIdx.x * 4;
  f32x4 z = {0.f, 0.f, 0.f, 0.f};
  #pragma unroll 4
  for (int i = 0; i < 48; i++)
    __builtin_nontemporal_store(z, (f32x4*)(dst + i * 1024));
}

// ---------------------------------------------------------------------------
// Convert: f32 -> bf16 for all inputs into ws; block 0 wave 0 computes
// per-batch ranges via binary search; blocks >= 4801 zero-fill attn rows
// 0..4095 (overlapped with the read-bound convert work).
// ---------------------------------------------------------------------------
__global__ __launch_bounds__(256) void convert_kernel(
    const float* __restrict__ prot, const float* __restrict__ mol,
    const float* __restrict__ Wq, const float* __restrict__ Wk,
    const float* __restrict__ Wv, const float* __restrict__ bq,
    const float* __restrict__ bk, const float* __restrict__ bv,
    const int* __restrict__ pb, const int* __restrict__ mb,
    int* __restrict__ rg, u16* __restrict__ cvt, float* __restrict__ dout)
{
  if (blockIdx.x >= 4801){
    fill_rows8(dout + (size_t)NPROT * HID, blockIdx.x - 4801);
    return;
  }
  int g = blockIdx.x * 256 + threadIdx.x;   // quad index
  const float* src = nullptr; u16* dst = nullptr; int off = 0;
  if      (g < 786432)  { src = prot; dst = cvt + PROT_O; off = g; }
  else if (g < 1179648) { src = mol;  dst = cvt + MOL_O;  off = g - 786432; }
  else if (g < 1196032) { src = Wq;   dst = cvt + WQ_O;   off = g - 1179648; }
  else if (g < 1212416) { src = Wk;   dst = cvt + WK_O;   off = g - 1196032; }
  else if (g < 1228800) { src = Wv;   dst = cvt + WV_O;   off = g - 1212416; }
  else if (g < 1228864) { src = bq;   dst = cvt + BQ_O;   off = g - 1228800; }
  else if (g < 1228928) { src = bk;   dst = cvt + BK_O;   off = g - 1228864; }
  else if (g < 1228992) { src = bv;   dst = cvt + BV_O;   off = g - 1228928; }
  if (src){
    f32x4 v = *(const f32x4*)(src + (size_t)off * 4);
    ushort4 o;
    o.x = f2b(v[0]); o.y = f2b(v[1]); o.z = f2b(v[2]); o.w = f2b(v[3]);
    *(ushort4*)(dst + (size_t)off * 4) = o;
  }

  if (blockIdx.x == 0 && threadIdx.x < 64){
    int t = threadIdx.x;
    const int* arr = (t < 32) ? pb : mb;
    int n          = (t < 32) ? NPROT : NMOL;
    int target     = (t & 31) + 1;
    int lo = 0, hi = n;
    while (lo < hi){                // lower_bound(target)
      int mid = (lo + hi) >> 1;
      if (arr[mid] < target) lo = mid + 1; else hi = mid;
    }
    int end = lo;
    int prev = __shfl(end, t - 1);  // end of batch b-1 == start of batch b
    int start = ((t & 31) == 0) ? 0 : prev;
    int b = t & 31;
    if (t < 32){ rg[b] = start; rg[32 + b] = end; }
    else       { rg[64 + b] = start; rg[96 + b] = end; }
  }
}

// ---------------------------------------------------------------------------
// Projections (bf16 in ws): out[i][j] = sum_k x[i][k]*W[j][k] + b[j]
// 1-D grid: x<1536 -> proj tiles; x>=1536 -> zero-fill attn rows 4096..8191.
// Wave computes a 16x64 tile. C/D layout: col=lane&15, row=(lane>>4)*4+reg.
// ---------------------------------------------------------------------------
__global__ __launch_bounds__(256) void proj_kernel(
    const u16* __restrict__ cvt,
    u16* __restrict__ Q, u16* __restrict__ K, u16* __restrict__ Vt,
    float* __restrict__ dout)
{
  __shared__ u16 tlds[4][64][18];
  if (blockIdx.x >= 1536){
    fill_rows8(dout + (size_t)NPROT * HID, blockIdx.x - 1536 + 512);
    return;
  }
  int rowblk = blockIdx.x >> 2, colblk = blockIdx.x & 3;
  int proj;
  if      (rowblk < 192){ proj = 0; }
  else if (rowblk < 288){ proj = 1; rowblk -= 192; }
  else                  { proj = 2; rowblk -= 288; }
  const u16 *X, *W, *B;
  if (proj == 0){ X = cvt + PROT_O; W = cvt + WQ_O; B = cvt + BQ_O; }
  else if (proj == 1){ X = cvt + MOL_O; W = cvt + WK_O; B = cvt + BK_O; }
  else { X = cvt + MOL_O; W = cvt + WV_O; B = cvt + BV_O; }

  int wave = threadIdx.x >> 6, lane = threadIdx.x & 63;
  int m = lane & 15, q = lane >> 4;
  int rowbase = rowblk * 64 + wave * 16;
  int colbase = colblk * 64;

  const u16* arow = X + (size_t)(rowbase + m) * HID;
  f32x4 acc[4] = {};
  for (int k0 = 0; k0 < HID; k0 += 32){
    bf16x8 a = *(const bf16x8*)(arow + k0 + q*8);
    #pragma unroll
    for (int ct = 0; ct < 4; ct++){
      bf16x8 b = *(const bf16x8*)(W + (size_t)(colbase + ct*16 + m) * HID + k0 + q*8);
      acc[ct] = __builtin_amdgcn_mfma_f32_16x16x32_bf16(a, b, acc[ct], 0, 0, 0);
    }
  }

  if (proj < 2){
    u16* O = (proj == 0) ? Q : K;
    #pragma unroll
    for (int ct = 0; ct < 4; ct++){
      int col = colbase + ct*16 + m;
      float bb = b2f(B[col]);
      #pragma unroll
      for (int r = 0; r < 4; r++){
        int row = rowbase + q*4 + r;
        O[(size_t)row * HID + col] = f2b(acc[ct][r] + bb);
      }
    }
  } else {
    #pragma unroll
    for (int ct = 0; ct < 4; ct++){
      int lc = ct*16 + m;
      float bb = b2f(B[colbase + lc]);
      #pragma unroll
      for (int r = 0; r < 4; r++)
        tlds[wave][lc][q*4 + r] = f2b(acc[ct][r] + bb);
    }
    __syncthreads();
    int col = colbase + lane;
    u32 packed[8];
    #pragma unroll
    for (int i = 0; i < 8; i++){
      u16 lo = tlds[wave][lane][2*i];
      u16 hi = tlds[wave][lane][2*i+1];
      packed[i] = (u32)lo | ((u32)hi << 16);
    }
    u16* dst = Vt + (size_t)col * NMOL + rowbase;
    uint4 v0 = {packed[0], packed[1], packed[2], packed[3]};
    uint4 v1 = {packed[4], packed[5], packed[6], packed[7]};
    *(uint4*)dst = v0;
    *(uint4*)(dst + 8) = v1;
  }
}

// ---------------------------------------------------------------------------
// Attention (f32 out). grid (40, 32): x<32 -> compute blocks for batch y;
// x>=32 -> fill blocks zeroing rows 8192..12287 (16 rows each), skipping
// each row's live cols [ms,me) (disjoint from the P stores -> no race).
// Compute: single QK^T, scores in registers:
//   A: S = QK^T (strip, regs) + row max      -> merge max via LDS
//   B: e = exp(s-gmx) (regs) + partial sums  -> merge sums via LDS
//   C: p = e*ginv -> attn global (NT) + P LDS (bf16)
//   D: PV with waves splitting HID (4 MFMA cols each) -> no O reduction
// ---------------------------------------------------------------------------
__global__ __launch_bounds__(256) void attn_kernel(
    const int* __restrict__ rg, const int* __restrict__ pb,
    const u16* __restrict__ Q, const u16* __restrict__ K,
    const u16* __restrict__ Vt, float* __restrict__ dout)
{
  __shared__ u16 P[16][392];        // P tile bf16, cols [bs,ce), pad->392
  __shared__ float mxw[4][16];
  __shared__ float smw[4][16];
  const float scale = 0.0625f;      // 1/sqrt(256)
  float* outf  = dout;
  float* attnf = dout + (size_t)NPROT * HID;

  if (blockIdx.x >= 32){
    // ---- fill block: 16 rows starting at 8192 + fid*16 ----
    int fid = (blockIdx.x - 32) + 8 * blockIdx.y;   // [0,256)
    int r0 = 8192 + fid * 16;
    f32x4 z = {0.f, 0.f, 0.f, 0.f};
    for (int rr = 0; rr < 16; rr++){
      int row = r0 + rr;
      int bb = pb[row];
      int ms = rg[64 + bb], me = rg[96 + bb];
      float* rowp = attnf + (size_t)row * NMOL;
      int mv = ms & ~3;
      for (int c = threadIdx.x * 4; c < mv; c += 1024)
        __builtin_nontemporal_store(z, (f32x4*)(rowp + c));
      for (int c = mv + threadIdx.x; c < ms; c += 256)
        rowp[c] = 0.f;
      int mu = (me + 3) & ~3;
      for (int c = me + threadIdx.x; c < mu && c < NMOL; c += 256)
        rowp[c] = 0.f;
      for (int c = mu + threadIdx.x * 4; c < NMOL; c += 1024)
        __builtin_nontemporal_store(z, (f32x4*)(rowp + c));
    }
    return;
  }

  int b = blockIdx.y;
  int ps = rg[b], pe = rg[32+b], ms = rg[64+b], me = rg[96+b];
  int Np = pe - ps, Nm = me - ms;
  if (Np <= 0) return;

  int wave = threadIdx.x >> 6, lane = threadIdx.x & 63;
  int m = lane & 15, q = lane >> 4;
  int ntiles = (Np + 15) >> 4;

  int bs = 0, ce = 0;
  if (Nm > 0){ bs = ms & ~31; ce = bs + ((me - bs + 31) & ~31); }  // ce <= NMOL

  for (int tile = blockIdx.x; tile < ntiles; tile += 32){
    int row0 = ps + tile * 16;
    int qr = min(row0 + m, NPROT - 1);
    const u16* qrow = Q + (size_t)qr * HID;
    bf16x8 qf[8];
    #pragma unroll
    for (int kk = 0; kk < 8; kk++)
      qf[kk] = *(const bf16x8*)(qrow + kk*32 + q*8);

    if (Nm > 0){
      int myj0 = bs + wave * 16;
      // ---- phase A: single QK^T pass, scores -> registers, track max ----
      f32x4 sreg[6];
      float mx[4] = {-1e30f, -1e30f, -1e30f, -1e30f};
      #pragma unroll
      for (int c = 0; c < 6; c++){
        int j0 = myj0 + 64*c;
        if (j0 < ce){
          int col = j0 + m;                         // col <= ce-1 < NMOL
          bool valid = (col >= ms) && (col < me);
          const u16* krow = K + (size_t)col * HID;
          f32x4 s0 = {0.f,0.f,0.f,0.f}, s1 = {0.f,0.f,0.f,0.f};
          #pragma unroll
          for (int kk = 0; kk < 4; kk++){
            bf16x8 kb0 = *(const bf16x8*)(krow + kk*32 + q*8);
            bf16x8 kb1 = *(const bf16x8*)(krow + (kk+4)*32 + q*8);
            s0 = __builtin_amdgcn_mfma_f32_16x16x32_bf16(qf[kk],   kb0, s0, 0, 0, 0);
            s1 = __builtin_amdgcn_mfma_f32_16x16x32_bf16(qf[kk+4], kb1, s1, 0, 0, 0);
          }
          f32x4 sv;
          #pragma unroll
          for (int r = 0; r < 4; r++)
            sv[r] = valid ? (s0[r] + s1[r]) * scale : -1e30f;
          sreg[c] = sv;
          float cm[4];
          #pragma unroll
          for (int r = 0; r < 4; r++) cm[r] = sv[r];
          #pragma unroll
          for (int d = 1; d < 16; d <<= 1)
            #pragma unroll
            for (int r = 0; r < 4; r++)
              cm[r] = fmaxf(cm[r], __shfl_xor(cm[r], d, 16));
          #pragma unroll
          for (int r = 0; r < 4; r++) mx[r] = fmaxf(mx[r], cm[r]);
        }
      }
      if (m == 0){
        #pragma unroll
        for (int r = 0; r < 4; r++) mxw[wave][q*4 + r] = mx[r];
      }
      __syncthreads();
      float gmx[4];
      #pragma unroll
      for (int r = 0; r < 4; r++){
        int row = q*4 + r;
        float M = mxw[0][row];
        #pragma unroll
        for (int w = 1; w < 4; w++) M = fmaxf(M, mxw[w][row]);
        gmx[r] = M;
      }

      // ---- phase B: exponentiate in regs + partial row sums ----
      float sm[4] = {0.f, 0.f, 0.f, 0.f};
      #pragma unroll
      for (int c = 0; c < 6; c++){
        int j0 = myj0 + 64*c;
        if (j0 < ce){
          f32x4 e;
          #pragma unroll
          for (int r = 0; r < 4; r++) e[r] = __expf(sreg[c][r] - gmx[r]);
          sreg[c] = e;
          float t[4];
          #pragma unroll
          for (int r = 0; r < 4; r++) t[r] = e[r];
          #pragma unroll
          for (int d = 1; d < 16; d <<= 1)
            #pragma unroll
            for (int r = 0; r < 4; r++)
              t[r] += __shfl_xor(t[r], d, 16);
          #pragma unroll
          for (int r = 0; r < 4; r++) sm[r] += t[r];
        }
      }
      if (m == 0){
        #pragma unroll
        for (int r = 0; r < 4; r++) smw[wave][q*4 + r] = sm[r];
      }
      __syncthreads();
      float ginv[4];
      #pragma unroll
      for (int r = 0; r < 4; r++){
        int row = q*4 + r;
        float S = smw[0][row] + smw[1][row] + smw[2][row] + smw[3][row];
        ginv[r] = (S > 0.f) ? (1.f / S) : 0.f;
      }

      // ---- phase C: normalize -> attn global + P LDS ----
      #pragma unroll
      for (int c = 0; c < 6; c++){
        int j0 = myj0 + 64*c;
        if (j0 < ce){
          int col = j0 + m;
          int jl = j0 - bs;
          bool valid = (col >= ms) && (col < me);
          #pragma unroll
          for (int r = 0; r < 4; r++){
            float p = sreg[c][r] * ginv[r];
            P[q*4 + r][jl + m] = f2b(p);
            int row = row0 + q*4 + r;
            if (valid && row < pe)
              __builtin_nontemporal_store(p, attnf + (size_t)row * NMOL + col);
          }
        }
      }
      __syncthreads();

      // ---- phase D: PV, waves split HID (ct = wave*4 .. wave*4+3) ----
      f32x4 oacc[4] = {};
      for (int j0 = bs; j0 < ce; j0 += 32){
        int jl = j0 - bs;
        bf16x8 a = *(const bf16x8*)(&P[m][jl + q*8]);
        #pragma unroll
        for (int c2 = 0; c2 < 4; c2++){
          int ct = wave*4 + c2;
          bf16x8 vb = *(const bf16x8*)(Vt + (size_t)(ct*16 + m) * NMOL + j0 + q*8);
          oacc[c2] = __builtin_amdgcn_mfma_f32_16x16x32_bf16(a, vb, oacc[c2], 0, 0, 0);
        }
      }
      #pragma unroll
      for (int c2 = 0; c2 < 4; c2++){
        int col = (wave*4 + c2)*16 + m;
        #pragma unroll
        for (int r = 0; r < 4; r++){
          int row = row0 + q*4 + r;
          if (row < pe) outf[(size_t)row * HID + col] = oacc[c2][r];
        }
      }
    } else {
      // no valid keys: O rows are zeros (waves split HID)
      #pragma unroll
      for (int c2 = 0; c2 < 4; c2++){
        int col = (wave*4 + c2)*16 + m;
        #pragma unroll
        for (int r = 0; r < 4; r++){
          int row = row0 + q*4 + r;
          if (row < pe) outf[(size_t)row * HID + col] = 0.f;
        }
      }
    }
    __syncthreads();   // protect P/mxw/smw reuse across tile iterations
  }
}

extern "C" void kernel_launch(void* const* d_in, const int* in_sizes, int n_in,
                              void* d_out, int out_size, void* d_ws, size_t ws_size,
                              hipStream_t stream)
{
  (void)in_sizes; (void)n_in; (void)out_size;
  const float* prot = (const float*)d_in[0];
  const float* mol  = (const float*)d_in[1];
  const int* pb     = (const int*)d_in[2];
  const int* mb     = (const int*)d_in[3];
  const float* Wq   = (const float*)d_in[4];
  const float* bq   = (const float*)d_in[5];
  const float* Wk   = (const float*)d_in[6];
  const float* bk   = (const float*)d_in[7];
  const float* Wv   = (const float*)d_in[8];
  const float* bv   = (const float*)d_in[9];

  const size_t need = 1024 + (size_t)END_O * 2;
  if (ws_size < need) return;

  char* ws = (char*)d_ws;
  int* rg  = (int*)ws;
  u16* cvt = (u16*)(ws + 1024);
  u16* Qp  = cvt + Q_O;
  u16* Kp  = cvt + K_O;
  u16* Vtp = cvt + VT_O;
  float* out = (float*)d_out;

  convert_kernel<<<dim3(4801 + 512), dim3(256), 0, stream>>>(
      prot, mol, Wq, Wk, Wv, bq, bk, bv, pb, mb, rg, cvt, out);
  proj_kernel<<<dim3(1536 + 512), dim3(256), 0, stream>>>(
      cvt, Qp, Kp, Vtp, out);
  attn_kernel<<<dim3(40, NB), dim3(256), 0, stream>>>(rg, pb, Qp, Kp, Vtp, out);
}